// Round 3
// baseline (387.207 us; speedup 1.0000x reference)
//
#include <hip/hip_runtime.h>
#include <hip/hip_bf16.h>

constexpr int B = 4;
constexpr int N = 1024;
constexpr int D = 1024;
constexpr int H = 16;
constexpr int DEPTH = 64;
constexpr int W = 32;
constexpr int LDQKV = 3072;   // fused q|k|v row stride
constexpr int KC = 3072;      // K-concat length: [hi | lo | hi] x [hi | hi | lo]

typedef __bf16 bf16x8 __attribute__((ext_vector_type(8)));
typedef float f32x4 __attribute__((ext_vector_type(4)));
typedef unsigned short us8 __attribute__((ext_vector_type(8)));

// ---------------------------------------------------------------------------
// async global->LDS, 16B per lane (wave-uniform LDS base, HW adds lane*16)
// ---------------------------------------------------------------------------
__device__ __forceinline__ void load_lds16(const void* g, void* l) {
  unsigned int lo = (unsigned int)(unsigned long long)l;
  __builtin_amdgcn_global_load_lds(
      (const __attribute__((address_space(1))) unsigned int*)g,
      (__attribute__((address_space(3))) unsigned int*)lo, 16, 0, 0);
}

// ---------------------------------------------------------------------------
// fp32 [M][1024] -> K-concat split bf16 [M][3072] = [hi | lo | hi]
// ---------------------------------------------------------------------------
__global__ __launch_bounds__(256) void cvt_split_cat(const float* __restrict__ x,
                                                     unsigned short* __restrict__ Ac) {
  const size_t i = ((size_t)blockIdx.x * 256 + threadIdx.x) * 8;
  const size_t row = i >> 10;
  const int col = (int)(i & 1023);
  float4 a = *(const float4*)(x + i);
  float4 b = *(const float4*)(x + i + 4);
  float xs[8] = {a.x, a.y, a.z, a.w, b.x, b.y, b.z, b.w};
  us8 hv, lv;
#pragma unroll
  for (int j = 0; j < 8; j++) {
    __bf16 h = (__bf16)xs[j];
    float rem = xs[j] - (float)h;
    __bf16 l = (__bf16)rem;
    hv[j] = __builtin_bit_cast(unsigned short, h);
    lv[j] = __builtin_bit_cast(unsigned short, l);
  }
  unsigned short* dst = Ac + row * KC + col;
  *(us8*)(dst) = hv;
  *(us8*)(dst + 2048) = hv;   // hi duplicate (multiplies B-lo third)
  *(us8*)(dst + 1024) = lv;   // lo (multiplies B-hi second third)
}

// ---------------------------------------------------------------------------
// weight [K=1024][Nn=1024] -> transposed K-concat split BT[rowOff+n][3072]
// = [hi | hi | lo].  64x64 tile via LDS.
// ---------------------------------------------------------------------------
__global__ __launch_bounds__(256) void txp_cvt_cat(const float* __restrict__ w,
                                                   unsigned short* __restrict__ bt,
                                                   int rowOff) {
  __shared__ float sf[64][65];
  const int t = threadIdx.x;
  const int tn = (blockIdx.x & 15) * 64;  // src col block
  const int tk = (blockIdx.x >> 4) * 64;  // src row block
#pragma unroll
  for (int i = 0; i < 4; i++) {
    int f = i * 256 + t;
    int r = f >> 4, c4 = (f & 15) * 4;
    float4 v = *(const float4*)(w + (size_t)(tk + r) * 1024 + tn + c4);
    sf[r][c4 + 0] = v.x; sf[r][c4 + 1] = v.y;
    sf[r][c4 + 2] = v.z; sf[r][c4 + 3] = v.w;
  }
  __syncthreads();
  const int n = t >> 2;            // out row (src col)
  const int kc = (t & 3) * 16;     // k chunk
  us8 hv[2], lv[2];
#pragma unroll
  for (int half = 0; half < 2; half++) {
#pragma unroll
    for (int j = 0; j < 8; j++) {
      float x = sf[kc + half * 8 + j][n];
      __bf16 h = (__bf16)x;
      float rem = x - (float)h;
      __bf16 l = (__bf16)rem;
      hv[half][j] = __builtin_bit_cast(unsigned short, h);
      lv[half][j] = __builtin_bit_cast(unsigned short, l);
    }
  }
  size_t dst = (size_t)(rowOff + tn + n) * KC + tk + kc;
  *(us8*)(bt + dst) = hv[0];
  *(us8*)(bt + dst + 8) = hv[1];
  *(us8*)(bt + dst + 1024) = hv[0];       // hi duplicate
  *(us8*)(bt + dst + 1024 + 8) = hv[1];
  *(us8*)(bt + dst + 2048) = lv[0];       // lo
  *(us8*)(bt + dst + 2048 + 8) = lv[1];
}

__global__ void bias_concat(const float* __restrict__ bq, const float* __restrict__ bk,
                            const float* __restrict__ bv, float* __restrict__ dst) {
  int i = blockIdx.x * 256 + threadIdx.x;
  dst[i] = i < 1024 ? bq[i] : (i < 2048 ? bk[i - 1024] : bv[i - 2048]);
}

// ---------------------------------------------------------------------------
// Plain bf16 MFMA GEMM (m97 structure): C[M][Nn] = A[M][K] @ BT[Nn][K]^T + bias
// 128x128 tile, BK=32, 4 waves, 16x16x32 MFMA, 4x4 frags/wave.
// LDS tiles [128][32] with granule swizzle k' = k ^ ((r>>1)&3) applied on the
// global SOURCE address (LDS dest linear for global_load_lds) and on ds_read.
// ---------------------------------------------------------------------------
__global__ __launch_bounds__(256) void gemm_bf16(
    const unsigned short* __restrict__ A, const unsigned short* __restrict__ BT,
    const float* __restrict__ bias, float* __restrict__ C,
    int K, int Nn) {
  __shared__ __align__(16) unsigned short sA[128 * 32];
  __shared__ __align__(16) unsigned short sB[128 * 32];

  const int tid = threadIdx.x;
  const int lane = tid & 63;
  const int wave = tid >> 6;
  const int wr = wave >> 1, wc = wave & 1;
  const int bm = blockIdx.y * 128, bn = blockIdx.x * 128;

  // staging: 8KB/tile = 8 chunks of (64 lanes x 16B); wave stages chunks w, w+4
  size_t aoff[2], boff[2];
  int ldsoff[2];
#pragma unroll
  for (int c = 0; c < 2; c++) {
    const int chunk = wave + 4 * c;
    const int e = chunk * 512 + lane * 8;   // linear LDS element
    const int r = e >> 5;                   // tile row
    const int kpos = (e >> 3) & 3;          // granule position in row
    const int ksrc = kpos ^ ((r >> 1) & 3); // swizzle: source granule
    aoff[c] = (size_t)(bm + r) * K + ksrc * 8;
    boff[c] = (size_t)(bn + r) * K + ksrc * 8;
    ldsoff[c] = chunk * 512;
  }

  const int fr = lane & 15;
  const int fkg = lane >> 4;

  f32x4 acc[4][4] = {};

  for (int k0 = 0; k0 < K; k0 += 32) {
#pragma unroll
    for (int c = 0; c < 2; c++) {
      load_lds16(A + aoff[c] + k0, sA + ldsoff[c]);
      load_lds16(BT + boff[c] + k0, sB + ldsoff[c]);
    }
    asm volatile("s_waitcnt vmcnt(0)" ::: "memory");
    __syncthreads();

    bf16x8 a[4], b[4];
#pragma unroll
    for (int m = 0; m < 4; m++) {
      const int r = wr * 64 + m * 16 + fr;
      const int off = r * 32 + ((fkg ^ ((r >> 1) & 3)) << 3);
      a[m] = *(const bf16x8*)(sA + off);
    }
#pragma unroll
    for (int n = 0; n < 4; n++) {
      const int r = wc * 64 + n * 16 + fr;
      const int off = r * 32 + ((fkg ^ ((r >> 1) & 3)) << 3);
      b[n] = *(const bf16x8*)(sB + off);
    }
#pragma unroll
    for (int m = 0; m < 4; m++)
#pragma unroll
      for (int n = 0; n < 4; n++)
        acc[m][n] = __builtin_amdgcn_mfma_f32_16x16x32_bf16(a[m], b[n], acc[m][n], 0, 0, 0);
    __syncthreads();
  }

  // epilogue: C/D layout col=lane&15, row=(lane>>4)*4+j
#pragma unroll
  for (int m = 0; m < 4; m++) {
    const int row = bm + wr * 64 + m * 16 + fkg * 4;
#pragma unroll
    for (int n = 0; n < 4; n++) {
      const int col = bn + wc * 64 + n * 16 + fr;
      const float bsv = bias[col];
#pragma unroll
      for (int j = 0; j < 4; j++)
        C[(size_t)(row + j) * Nn + col] = acc[m][n][j] + bsv;
    }
  }
}

// ---------------------------------------------------------------------------
// Vsum[b, d] = sum_n v[b, n, d]   (v inside qkv, row stride LDQKV)
// ---------------------------------------------------------------------------
__global__ __launch_bounds__(256) void vsum_kernel(const float* __restrict__ v,
                                                   float* __restrict__ vsum) {
  const int idx = blockIdx.x * 256 + threadIdx.x;  // b*D + d
  const int b = idx >> 10;
  const int d = idx & (D - 1);
  const float* p = v + (size_t)b * N * LDQKV + d;
  float s = 0.f;
  for (int n = 0; n < N; n++) s += p[(size_t)n * LDQKV];
  vsum[idx] = s;
}

// ---------------------------------------------------------------------------
// pass1: gather-dot over 32 keys, closed-form full-row softmax, out via Vsum
// ---------------------------------------------------------------------------
__global__ __launch_bounds__(64) void attn_pass1(
    const float* __restrict__ qkv, const float* __restrict__ vsum,
    const int* __restrict__ graph, float* __restrict__ pbuf,
    float* __restrict__ basebuf, float* __restrict__ outbuf) {
  const int bid = blockIdx.x;  // (b*H + h)*N + n
  const int n = bid & (N - 1);
  const int h = (bid >> 10) & (H - 1);
  const int b = bid >> 14;
  const int lane = threadIdx.x;

  __shared__ float q_sh[DEPTH];
  __shared__ int g_sh[W];
  __shared__ float p_sh[W];

  const float* qrow = qkv + (size_t)(b * N + n) * LDQKV + h * DEPTH;
  q_sh[lane] = qrow[lane];
  if (lane < W) g_sh[lane] = graph[n * W + lane];
  __syncthreads();

  const int w = lane >> 1;
  const int half = lane & 1;
  const float* krow =
      qkv + 1024 + (size_t)(b * N + g_sh[w]) * LDQKV + h * DEPTH + half * 32;
  float acc = 0.f;
#pragma unroll
  for (int j4 = 0; j4 < 8; j4++) {
    float4 kv = *(const float4*)(krow + j4 * 4);
    const float* qh = &q_sh[half * 32 + j4 * 4];
    acc += kv.x * qh[0] + kv.y * qh[1] + kv.z * qh[2] + kv.w * qh[3];
  }
  acc += __shfl_xor(acc, 1);
  const float dot = acc * 0.125f;

  float m = dot;
#pragma unroll
  for (int off = 2; off < 64; off <<= 1) m = fmaxf(m, __shfl_xor(m, off));
  m = fmaxf(m, 0.f);

  const float e = expf(dot - m);
  float s = e;
#pragma unroll
  for (int off = 1; off < 64; off <<= 1) s += __shfl_xor(s, off);
  s *= 0.5f;

  const float em = expf(-m);
  const float Z = (float)(N - W) * em + s;
  const float inv = 1.f / Z;
  const float base = em * inv;
  const float pw = e * inv;

  if (half == 0) p_sh[w] = pw;
  __syncthreads();

  if (half == 0) pbuf[(size_t)bid * W + w] = pw;
  if (lane == 0) basebuf[bid] = base;

  const float* vbase = qkv + 2048;
  float ov = base * vsum[b * D + h * DEPTH + lane];
#pragma unroll 4
  for (int ww = 0; ww < W; ww++) {
    ov += (p_sh[ww] - base) *
          vbase[(size_t)(b * N + g_sh[ww]) * LDQKV + h * DEPTH + lane];
  }
  outbuf[(size_t)(b * N + n) * D + h * DEPTH + lane] = ov;
}

// ---------------------------------------------------------------------------
// attn row fill: base everywhere, p_w at graph positions
// ---------------------------------------------------------------------------
__global__ __launch_bounds__(256) void attn_fill(
    const float* __restrict__ pbuf, const float* __restrict__ basebuf,
    const int* __restrict__ graph, float* __restrict__ attn) {
  const int bid = blockIdx.x;
  const int n = bid & (N - 1);
  __shared__ float row[N];

  const float base = basebuf[bid];
  float4 b4 = {base, base, base, base};
  float4* row4 = (float4*)row;
  row4[threadIdx.x] = b4;
  __syncthreads();
  if (threadIdx.x < W) {
    const int g = graph[n * W + threadIdx.x];
    row[g] = pbuf[(size_t)bid * W + threadIdx.x];
  }
  __syncthreads();
  float4* dst = (float4*)(attn + (size_t)bid * N);
  dst[threadIdx.x] = row4[threadIdx.x];
}

// ---------------------------------------------------------------------------
extern "C" void kernel_launch(void* const* d_in, const int* in_sizes, int n_in,
                              void* d_out, int out_size, void* d_ws, size_t ws_size,
                              hipStream_t stream) {
  const float* hidden = (const float*)d_in[0];
  const float* wq = (const float*)d_in[1];
  const float* bq = (const float*)d_in[2];
  const float* wk = (const float*)d_in[3];
  const float* bk = (const float*)d_in[4];
  const float* wv = (const float*)d_in[5];
  const float* bv = (const float*)d_in[6];
  const float* wo = (const float*)d_in[7];
  const float* bo = (const float*)d_in[8];
  const int* graph = (const int*)d_in[9];

  float* out0 = (float*)d_out;                 // (B,N,D)
  float* attnp = out0 + (size_t)B * N * D;     // (B,H,N,N) — also scratch arena

  // scratch carved from attn region (67.1M floats; fully rewritten by attn_fill)
  const size_t M1 = (size_t)1024 * 1024;
  float* qkv = attnp;                            // [4096][3072] f32  (12M f)
  float* ob = attnp + 12 * M1;                   // [4096][1024] f32  (4M f)
  unsigned short* Ac = (unsigned short*)(attnp + 16 * M1);   // [4096][3072] (6M f)
  unsigned short* BTc = (unsigned short*)(attnp + 22 * M1);  // [3072][3072] (4.5M f)
  unsigned short* Oc = (unsigned short*)(attnp + 27 * M1);   // [4096][3072] (6M f)
  unsigned short* WoTc = (unsigned short*)(attnp + 33 * M1); // [1024][3072] (1.5M f)
  float* biasq = attnp + 35 * M1;                // 3072 f32

  // small workspace
  float* pbuf = (float*)d_ws;                  // B*H*N*W
  float* basebuf = pbuf + (size_t)B * H * N * W;
  float* vsumb = basebuf + (size_t)B * H * N;

  cvt_split_cat<<<2048, 256, 0, stream>>>(hidden, Ac);
  txp_cvt_cat<<<256, 256, 0, stream>>>(wq, BTc, 0);
  txp_cvt_cat<<<256, 256, 0, stream>>>(wk, BTc, 1024);
  txp_cvt_cat<<<256, 256, 0, stream>>>(wv, BTc, 2048);
  txp_cvt_cat<<<256, 256, 0, stream>>>(wo, WoTc, 0);
  bias_concat<<<12, 256, 0, stream>>>(bq, bk, bv, biasq);

  gemm_bf16<<<dim3(24, 32), 256, 0, stream>>>(Ac, BTc, biasq, qkv, KC, 3072);

  vsum_kernel<<<16, 256, 0, stream>>>(qkv + 2048, vsumb);
  attn_pass1<<<B * H * N, 64, 0, stream>>>(qkv, vsumb, graph, pbuf, basebuf, ob);

  cvt_split_cat<<<2048, 256, 0, stream>>>(ob, Oc);
  gemm_bf16<<<dim3(8, 32), 256, 0, stream>>>(Oc, WoTc, bo, out0, KC, 1024);

  attn_fill<<<B * H * N, 256, 0, stream>>>(pbuf, basebuf, graph, attnp);
}

// Round 6
// 305.480 us; speedup vs baseline: 1.2675x; 1.2675x over previous
//
#include <hip/hip_runtime.h>
#include <hip/hip_bf16.h>

constexpr int B = 4;
constexpr int N = 1024;
constexpr int D = 1024;
constexpr int H = 16;
constexpr int DEPTH = 64;
constexpr int W = 32;
constexpr int LDQKV = 3072;   // fused q|k|v row stride

typedef __bf16 bf16x8 __attribute__((ext_vector_type(8)));
typedef float f32x4 __attribute__((ext_vector_type(4)));
typedef unsigned short us8 __attribute__((ext_vector_type(8)));

// ---------------------------------------------------------------------------
// async global->LDS, 16B per lane (wave-uniform LDS base, HW adds lane*16)
// ---------------------------------------------------------------------------
__device__ __forceinline__ void load_lds16(const void* g, void* l) {
  unsigned int lo = (unsigned int)(unsigned long long)l;
  __builtin_amdgcn_global_load_lds(
      (const __attribute__((address_space(1))) unsigned int*)g,
      (__attribute__((address_space(3))) unsigned int*)lo, 16, 0, 0);
}

// ---------------------------------------------------------------------------
// split fp32 x -> bf16 hi + bf16 lo
// ---------------------------------------------------------------------------
__global__ __launch_bounds__(256) void cvt_split(const float* __restrict__ x,
                                                 unsigned short* __restrict__ hi,
                                                 unsigned short* __restrict__ lo) {
  const size_t i = ((size_t)blockIdx.x * 256 + threadIdx.x) * 8;
  float4 a = *(const float4*)(x + i);
  float4 b = *(const float4*)(x + i + 4);
  float xs[8] = {a.x, a.y, a.z, a.w, b.x, b.y, b.z, b.w};
  us8 hv, lv;
#pragma unroll
  for (int j = 0; j < 8; j++) {
    __bf16 h = (__bf16)xs[j];
    float rem = xs[j] - (float)h;
    __bf16 l = (__bf16)rem;
    hv[j] = __builtin_bit_cast(unsigned short, h);
    lv[j] = __builtin_bit_cast(unsigned short, l);
  }
  *(us8*)(hi + i) = hv;
  *(us8*)(lo + i) = lv;
}

// ---------------------------------------------------------------------------
// weight [K=1024][N=1024] -> transposed split BT[rowOff+n][k] (bf16 hi/lo)
// ---------------------------------------------------------------------------
__global__ __launch_bounds__(256) void txp_cvt(const float* __restrict__ w,
                                               unsigned short* __restrict__ bth,
                                               unsigned short* __restrict__ btl,
                                               int rowOff) {
  __shared__ float sf[64][65];
  const int t = threadIdx.x;
  const int tn = (blockIdx.x & 15) * 64;  // src col block
  const int tk = (blockIdx.x >> 4) * 64;  // src row block
#pragma unroll
  for (int i = 0; i < 4; i++) {
    int f = i * 256 + t;
    int r = f >> 4, c4 = (f & 15) * 4;
    float4 v = *(const float4*)(w + (size_t)(tk + r) * 1024 + tn + c4);
    sf[r][c4 + 0] = v.x; sf[r][c4 + 1] = v.y;
    sf[r][c4 + 2] = v.z; sf[r][c4 + 3] = v.w;
  }
  __syncthreads();
  const int n = t >> 2;            // out row (src col)
  const int kc = (t & 3) * 16;     // k chunk
  us8 hv[2], lv[2];
#pragma unroll
  for (int half = 0; half < 2; half++) {
#pragma unroll
    for (int j = 0; j < 8; j++) {
      float x = sf[kc + half * 8 + j][n];
      __bf16 h = (__bf16)x;
      float rem = x - (float)h;
      __bf16 l = (__bf16)rem;
      hv[half][j] = __builtin_bit_cast(unsigned short, h);
      lv[half][j] = __builtin_bit_cast(unsigned short, l);
    }
  }
  size_t dst = (size_t)(rowOff + tn + n) * 1024 + tk + kc;
  *(us8*)(bth + dst) = hv[0];
  *(us8*)(bth + dst + 8) = hv[1];
  *(us8*)(btl + dst) = lv[0];
  *(us8*)(btl + dst + 8) = lv[1];
}

__global__ void bias_concat(const float* __restrict__ bq, const float* __restrict__ bk,
                            const float* __restrict__ bv, float* __restrict__ dst) {
  int i = blockIdx.x * 256 + threadIdx.x;
  dst[i] = i < 1024 ? bq[i] : (i < 2048 ? bk[i - 1024] : bv[i - 2048]);
}

// ---------------------------------------------------------------------------
// Split-bf16 MFMA GEMM (round-2 proven): C = Ah@Bh + Ah@Bl + Al@Bh + bias
// 128x128 tile, BK=32, 4 waves, 16x16x32 MFMA, 4x4 frags/wave.
// Granule swizzle k' = k ^ ((r>>1)&3) via pre-swizzled global src + ds_read.
// T1 XCD-aware block swizzle (requires nwg % 8 == 0 — true for both launches).
// ---------------------------------------------------------------------------
__global__ __launch_bounds__(256) void gemm_split(
    const unsigned short* __restrict__ Ah, const unsigned short* __restrict__ Al,
    const unsigned short* __restrict__ Bth, const unsigned short* __restrict__ Btl,
    const float* __restrict__ bias, float* __restrict__ C,
    int K, int Nn) {
  __shared__ __align__(16) unsigned short sAh[128 * 32];
  __shared__ __align__(16) unsigned short sAl[128 * 32];
  __shared__ __align__(16) unsigned short sBh[128 * 32];
  __shared__ __align__(16) unsigned short sBl[128 * 32];

  const int tid = threadIdx.x;
  const int lane = tid & 63;
  const int wave = tid >> 6;
  const int wr = wave >> 1, wc = wave & 1;

  // XCD-aware swizzle: consecutive swizzled ids land on one XCD's L2
  const int gx = gridDim.x;
  const int nwg = gx * gridDim.y;
  int bid = blockIdx.y * gx + blockIdx.x;
  bid = (bid & 7) * (nwg >> 3) + (bid >> 3);
  const int bm = (bid / gx) * 128;
  const int bn = (bid % gx) * 128;

  size_t aoff[2], boff[2];
  int ldsoff[2];
#pragma unroll
  for (int c = 0; c < 2; c++) {
    const int chunk = wave + 4 * c;
    const int e = chunk * 512 + lane * 8;   // linear LDS element
    const int r = e >> 5;                   // tile row
    const int kpos = (e >> 3) & 3;          // granule position in row
    const int ksrc = kpos ^ ((r >> 1) & 3); // swizzle: source granule
    aoff[c] = (size_t)(bm + r) * K + ksrc * 8;
    boff[c] = (size_t)(bn + r) * K + ksrc * 8;
    ldsoff[c] = chunk * 512;
  }

  const int fr = lane & 15;
  const int fkg = lane >> 4;

  f32x4 acc[4][4] = {};

  for (int k0 = 0; k0 < K; k0 += 32) {
#pragma unroll
    for (int c = 0; c < 2; c++) {
      load_lds16(Ah + aoff[c] + k0, sAh + ldsoff[c]);
      load_lds16(Al + aoff[c] + k0, sAl + ldsoff[c]);
      load_lds16(Bth + boff[c] + k0, sBh + ldsoff[c]);
      load_lds16(Btl + boff[c] + k0, sBl + ldsoff[c]);
    }
    asm volatile("s_waitcnt vmcnt(0)" ::: "memory");
    __syncthreads();

    bf16x8 ah[4], al[4], bh[4], bl[4];
#pragma unroll
    for (int m = 0; m < 4; m++) {
      const int r = wr * 64 + m * 16 + fr;
      const int off = r * 32 + ((fkg ^ ((r >> 1) & 3)) << 3);
      ah[m] = *(const bf16x8*)(sAh + off);
      al[m] = *(const bf16x8*)(sAl + off);
    }
#pragma unroll
    for (int n = 0; n < 4; n++) {
      const int r = wc * 64 + n * 16 + fr;
      const int off = r * 32 + ((fkg ^ ((r >> 1) & 3)) << 3);
      bh[n] = *(const bf16x8*)(sBh + off);
      bl[n] = *(const bf16x8*)(sBl + off);
    }
#pragma unroll
    for (int m = 0; m < 4; m++)
#pragma unroll
      for (int n = 0; n < 4; n++) {
        acc[m][n] = __builtin_amdgcn_mfma_f32_16x16x32_bf16(ah[m], bh[n], acc[m][n], 0, 0, 0);
        acc[m][n] = __builtin_amdgcn_mfma_f32_16x16x32_bf16(ah[m], bl[n], acc[m][n], 0, 0, 0);
        acc[m][n] = __builtin_amdgcn_mfma_f32_16x16x32_bf16(al[m], bh[n], acc[m][n], 0, 0, 0);
      }
    __syncthreads();
  }

#pragma unroll
  for (int m = 0; m < 4; m++) {
    const int row = bm + wr * 64 + m * 16 + fkg * 4;
#pragma unroll
    for (int n = 0; n < 4; n++) {
      const int col = bn + wc * 64 + n * 16 + fr;
      const float bsv = bias[col];
#pragma unroll
      for (int j = 0; j < 4; j++)
        C[(size_t)(row + j) * Nn + col] = acc[m][n][j] + bsv;
    }
  }
}

// ---------------------------------------------------------------------------
// Vsum two-stage: part[b,chunk,d] = sum of 64 rows; then combine.
// ---------------------------------------------------------------------------
__global__ __launch_bounds__(256) void vsum_part(const float* __restrict__ v,
                                                 float* __restrict__ part) {
  const int b = blockIdx.x >> 4;
  const int chunk = blockIdx.x & 15;
  const int d4 = threadIdx.x * 4;
  const float* p = v + (size_t)b * N * LDQKV + (size_t)chunk * 64 * LDQKV + d4;
  float4 s = {0.f, 0.f, 0.f, 0.f};
#pragma unroll 8
  for (int n = 0; n < 64; n++) {
    float4 t = *(const float4*)(p + (size_t)n * LDQKV);
    s.x += t.x; s.y += t.y; s.z += t.z; s.w += t.w;
  }
  *(float4*)(part + (size_t)blockIdx.x * 1024 + d4) = s;
}

__global__ __launch_bounds__(256) void vsum_comb(const float* __restrict__ part,
                                                 float* __restrict__ vsum) {
  const int i = blockIdx.x * 256 + threadIdx.x;  // b*1024 + d
  const int b = i >> 10, d = i & 1023;
  float s = 0.f;
#pragma unroll
  for (int c = 0; c < 16; c++) s += part[(size_t)(b * 16 + c) * 1024 + d];
  vsum[i] = s;
}

// ---------------------------------------------------------------------------
// pass1: gather-dot over 32 keys, closed-form full-row softmax;
// writes p/base and the split-bf16 O-GEMM input (Oh/Ol) directly.
// ---------------------------------------------------------------------------
__global__ __launch_bounds__(64) void attn_pass1(
    const float* __restrict__ qkv, const float* __restrict__ vsum,
    const int* __restrict__ graph, float* __restrict__ pbuf,
    float* __restrict__ basebuf, unsigned short* __restrict__ Oh,
    unsigned short* __restrict__ Ol) {
  const int bid = blockIdx.x;  // (b*H + h)*N + n
  const int n = bid & (N - 1);
  const int h = (bid >> 10) & (H - 1);
  const int b = bid >> 14;
  const int lane = threadIdx.x;

  __shared__ float q_sh[DEPTH];
  __shared__ int g_sh[W];
  __shared__ float p_sh[W];

  const float* qrow = qkv + (size_t)(b * N + n) * LDQKV + h * DEPTH;
  q_sh[lane] = qrow[lane];
  if (lane < W) g_sh[lane] = graph[n * W + lane];
  __syncthreads();

  const int w = lane >> 1;
  const int half = lane & 1;
  const float* krow =
      qkv + 1024 + (size_t)(b * N + g_sh[w]) * LDQKV + h * DEPTH + half * 32;
  float acc = 0.f;
#pragma unroll
  for (int j4 = 0; j4 < 8; j4++) {
    float4 kv = *(const float4*)(krow + j4 * 4);
    const float* qh = &q_sh[half * 32 + j4 * 4];
    acc += kv.x * qh[0] + kv.y * qh[1] + kv.z * qh[2] + kv.w * qh[3];
  }
  acc += __shfl_xor(acc, 1);
  const float dot = acc * 0.125f;

  float m = dot;
#pragma unroll
  for (int off = 2; off < 64; off <<= 1) m = fmaxf(m, __shfl_xor(m, off));
  m = fmaxf(m, 0.f);

  const float e = expf(dot - m);
  float s = e;
#pragma unroll
  for (int off = 1; off < 64; off <<= 1) s += __shfl_xor(s, off);
  s *= 0.5f;

  const float em = expf(-m);
  const float Z = (float)(N - W) * em + s;
  const float inv = 1.f / Z;
  const float base = em * inv;
  const float pw = e * inv;

  if (half == 0) p_sh[w] = pw;
  __syncthreads();

  if (half == 0) pbuf[(size_t)bid * W + w] = pw;
  if (lane == 0) basebuf[bid] = base;

  const float* vbase = qkv + 2048;
  const int col = h * DEPTH + lane;
  float ov = base * vsum[b * D + col];
#pragma unroll 4
  for (int ww = 0; ww < W; ww++) {
    ov += (p_sh[ww] - base) *
          vbase[(size_t)(b * N + g_sh[ww]) * LDQKV + col];
  }
  // split directly into the O-GEMM A operand
  __bf16 hh = (__bf16)ov;
  float rem = ov - (float)hh;
  __bf16 ll = (__bf16)rem;
  const size_t oidx = (size_t)(b * N + n) * D + col;
  Oh[oidx] = __builtin_bit_cast(unsigned short, hh);
  Ol[oidx] = __builtin_bit_cast(unsigned short, ll);
}

// ---------------------------------------------------------------------------
// attn row fill: base everywhere, p_w at graph positions. NT stores via
// native ext_vector f32x4 (HIP float4 class is rejected by the builtin).
// ---------------------------------------------------------------------------
__global__ __launch_bounds__(256) void attn_fill(
    const float* __restrict__ pbuf, const float* __restrict__ basebuf,
    const int* __restrict__ graph, float* __restrict__ attn) {
  const int bid = blockIdx.x;
  const int n = bid & (N - 1);
  __shared__ float row[N];

  const float base = basebuf[bid];
  f32x4 b4 = {base, base, base, base};
  f32x4* row4 = (f32x4*)row;
  row4[threadIdx.x] = b4;
  __syncthreads();
  if (threadIdx.x < W) {
    const int g = graph[n * W + threadIdx.x];
    row[g] = pbuf[(size_t)bid * W + threadIdx.x];
  }
  __syncthreads();
  f32x4* dst = (f32x4*)(attn + (size_t)bid * N);
  __builtin_nontemporal_store(row4[threadIdx.x], dst + threadIdx.x);
}

// ---------------------------------------------------------------------------
extern "C" void kernel_launch(void* const* d_in, const int* in_sizes, int n_in,
                              void* d_out, int out_size, void* d_ws, size_t ws_size,
                              hipStream_t stream) {
  const float* hidden = (const float*)d_in[0];
  const float* wq = (const float*)d_in[1];
  const float* bq = (const float*)d_in[2];
  const float* wk = (const float*)d_in[3];
  const float* bk = (const float*)d_in[4];
  const float* wv = (const float*)d_in[5];
  const float* bv = (const float*)d_in[6];
  const float* wo = (const float*)d_in[7];
  const float* bo = (const float*)d_in[8];
  const int* graph = (const int*)d_in[9];

  float* out0 = (float*)d_out;                 // (B,N,D) final output
  float* attnp = out0 + (size_t)B * N * D;     // (B,H,N,N) — also scratch arena

  // scratch carved from attn region (64M floats; fully rewritten by attn_fill)
  const size_t M1 = (size_t)1024 * 1024;
  float* qkv = attnp;                                        // [4096][3072] f32
  unsigned short* Ahid = (unsigned short*)(attnp + 12 * M1); // [4096][1024]
  unsigned short* Alid = Ahid + 4 * M1;
  unsigned short* BTh = (unsigned short*)(attnp + 16 * M1);  // [3072][1024]
  unsigned short* BTl = BTh + 3 * M1;
  unsigned short* WoTh = (unsigned short*)(attnp + 19 * M1); // [1024][1024]
  unsigned short* WoTl = WoTh + M1;
  unsigned short* Oh = (unsigned short*)(attnp + 20 * M1);   // [4096][1024]
  unsigned short* Ol = Oh + 4 * M1;
  float* biasq = attnp + 24 * M1;                            // 3072
  float* vpart = attnp + 24 * M1 + 8192;                     // [64][1024]

  // small workspace (8.67 MB — proven size from rounds 1-3)
  float* pbuf = (float*)d_ws;                  // B*H*N*W
  float* basebuf = pbuf + (size_t)B * H * N * W;
  float* vsumb = basebuf + (size_t)B * H * N;

  // converts
  cvt_split<<<2048, 256, 0, stream>>>(hidden, Ahid, Alid);
  txp_cvt<<<256, 256, 0, stream>>>(wq, BTh, BTl, 0);
  txp_cvt<<<256, 256, 0, stream>>>(wk, BTh, BTl, 1024);
  txp_cvt<<<256, 256, 0, stream>>>(wv, BTh, BTl, 2048);
  txp_cvt<<<256, 256, 0, stream>>>(wo, WoTh, WoTl, 0);
  bias_concat<<<12, 256, 0, stream>>>(bq, bk, bv, biasq);

  // fused projection: qkv = hidden @ [Wq | Wk | Wv] + [bq | bk | bv]
  gemm_split<<<dim3(24, 32), 256, 0, stream>>>(Ahid, Alid, BTh, BTl, biasq,
                                               qkv, 1024, 3072);

  vsum_part<<<64, 256, 0, stream>>>(qkv + 2048, vpart);
  vsum_comb<<<16, 256, 0, stream>>>(vpart, vsumb);

  attn_pass1<<<B * H * N, 64, 0, stream>>>(qkv, vsumb, graph, pbuf, basebuf,
                                           Oh, Ol);

  // O-projection
  gemm_split<<<dim3(8, 32), 256, 0, stream>>>(Oh, Ol, WoTh, WoTl, bo,
                                              out0, 1024, 1024);

  attn_fill<<<B * H * N, 256, 0, stream>>>(pbuf, basebuf, graph, attnp);
}

// Round 7
// 260.465 us; speedup vs baseline: 1.4866x; 1.1728x over previous
//
#include <hip/hip_runtime.h>
#include <hip/hip_bf16.h>

constexpr int B = 4;
constexpr int N = 1024;
constexpr int D = 1024;
constexpr int H = 16;
constexpr int DEPTH = 64;
constexpr int W = 32;
constexpr int LDQKV = 3072;   // fused q|k|v row stride

typedef _Float16 f16x8 __attribute__((ext_vector_type(8)));
typedef float f32x4 __attribute__((ext_vector_type(4)));
typedef unsigned short us8 __attribute__((ext_vector_type(8)));

// ---------------------------------------------------------------------------
// async global->LDS, 16B per lane (wave-uniform LDS base, HW adds lane*16)
// ---------------------------------------------------------------------------
__device__ __forceinline__ void load_lds16(const void* g, void* l) {
  unsigned int lo = (unsigned int)(unsigned long long)l;
  __builtin_amdgcn_global_load_lds(
      (const __attribute__((address_space(1))) unsigned int*)g,
      (__attribute__((address_space(3))) unsigned int*)lo, 16, 0, 0);
}

// ---------------------------------------------------------------------------
// fp32 -> fp16 (single hi plane), 8 elems/thread
// ---------------------------------------------------------------------------
__global__ __launch_bounds__(256) void cvt_half(const float* __restrict__ x,
                                                unsigned short* __restrict__ o) {
  const size_t i = ((size_t)blockIdx.x * 256 + threadIdx.x) * 8;
  float4 a = *(const float4*)(x + i);
  float4 b = *(const float4*)(x + i + 4);
  float xs[8] = {a.x, a.y, a.z, a.w, b.x, b.y, b.z, b.w};
  us8 hv;
#pragma unroll
  for (int j = 0; j < 8; j++) {
    _Float16 h = (_Float16)xs[j];
    hv[j] = __builtin_bit_cast(unsigned short, h);
  }
  *(us8*)(o + i) = hv;
}

// ---------------------------------------------------------------------------
// weight [K=1024][N=1024] -> transposed fp16 split BT[rowOff+n][k]:
// hi = (f16)w ; lo = (f16)((w - hi) * 1024)   (scaled to stay fp16-normal)
// ---------------------------------------------------------------------------
__global__ __launch_bounds__(256) void txp_cvt_h(const float* __restrict__ w,
                                                 unsigned short* __restrict__ bth,
                                                 unsigned short* __restrict__ btl,
                                                 int rowOff) {
  __shared__ float sf[64][65];
  const int t = threadIdx.x;
  const int tn = (blockIdx.x & 15) * 64;  // src col block
  const int tk = (blockIdx.x >> 4) * 64;  // src row block
#pragma unroll
  for (int i = 0; i < 4; i++) {
    int f = i * 256 + t;
    int r = f >> 4, c4 = (f & 15) * 4;
    float4 v = *(const float4*)(w + (size_t)(tk + r) * 1024 + tn + c4);
    sf[r][c4 + 0] = v.x; sf[r][c4 + 1] = v.y;
    sf[r][c4 + 2] = v.z; sf[r][c4 + 3] = v.w;
  }
  __syncthreads();
  const int n = t >> 2;            // out row (src col)
  const int kc = (t & 3) * 16;     // k chunk
  us8 hv[2], lv[2];
#pragma unroll
  for (int half = 0; half < 2; half++) {
#pragma unroll
    for (int j = 0; j < 8; j++) {
      float x = sf[kc + half * 8 + j][n];
      _Float16 h = (_Float16)x;
      _Float16 l = (_Float16)((x - (float)h) * 1024.0f);
      hv[half][j] = __builtin_bit_cast(unsigned short, h);
      lv[half][j] = __builtin_bit_cast(unsigned short, l);
    }
  }
  size_t dst = (size_t)(rowOff + tn + n) * 1024 + tk + kc;
  *(us8*)(bth + dst) = hv[0];
  *(us8*)(bth + dst + 8) = hv[1];
  *(us8*)(btl + dst) = lv[0];
  *(us8*)(btl + dst + 8) = lv[1];
}

__global__ void bias_concat(const float* __restrict__ bq, const float* __restrict__ bk,
                            const float* __restrict__ bv, float* __restrict__ dst) {
  int i = blockIdx.x * 256 + threadIdx.x;
  dst[i] = i < 1024 ? bq[i] : (i < 2048 ? bk[i - 1024] : bv[i - 2048]);
}

// ---------------------------------------------------------------------------
// fp16 2-term split MFMA GEMM: C = Ah@Bh + (Ah*2^-10)@(Bl*2^10) + bias
//                                = Ah@(Bh+Bl_true) + bias
// 128x128 tile, BK=64, 4 waves, 16x16x32 f16 MFMA, 4x4 frags/wave.
// 3 LDS planes [128][64] (48 KB). Granule swizzle g' = g ^ (r&7) applied on
// the global SOURCE (LDS dest linear for global_load_lds) and on ds_read.
// T1 XCD-aware block swizzle (nwg % 8 == 0 for both launches).
// ---------------------------------------------------------------------------
__global__ __launch_bounds__(256) void gemm_f16(
    const unsigned short* __restrict__ A16, const unsigned short* __restrict__ BTh,
    const unsigned short* __restrict__ BTl, const float* __restrict__ bias,
    float* __restrict__ C, int K, int Nn) {
  __shared__ __align__(16) unsigned short sA[128 * 64];
  __shared__ __align__(16) unsigned short sBh[128 * 64];
  __shared__ __align__(16) unsigned short sBl[128 * 64];

  const int tid = threadIdx.x;
  const int lane = tid & 63;
  const int wave = tid >> 6;
  const int wr = wave >> 1, wc = wave & 1;

  // XCD-aware swizzle
  const int gx = gridDim.x;
  const int nwg = gx * gridDim.y;
  int bid = blockIdx.y * gx + blockIdx.x;
  bid = (bid & 7) * (nwg >> 3) + (bid >> 3);
  const int bm = (bid / gx) * 128;
  const int bn = (bid % gx) * 128;

  // staging: each plane = 16 KB = 16 chunks of (64 lanes x 16B);
  // wave stages chunks {wave + 4c} of each plane.
  size_t aoff[4], boff[4];
  int ldsoff[4];
#pragma unroll
  for (int c = 0; c < 4; c++) {
    const int chunk = wave + 4 * c;             // 0..15
    const int lrow = chunk * 8 + (lane >> 3);   // tile row 0..127
    const int p = lane & 7;                     // granule pos in row
    const int ks = p ^ (lrow & 7);              // swizzled source granule
    aoff[c] = (size_t)(bm + lrow) * K + ks * 8;
    boff[c] = (size_t)(bn + lrow) * K + ks * 8;
    ldsoff[c] = chunk * 512;
  }

  const int fr = lane & 15;
  const int fkg = lane >> 4;

  f32x4 acc[4][4] = {};

  for (int k0 = 0; k0 < K; k0 += 64) {
#pragma unroll
    for (int c = 0; c < 4; c++) {
      load_lds16(A16 + aoff[c] + k0, sA + ldsoff[c]);
      load_lds16(BTh + boff[c] + k0, sBh + ldsoff[c]);
      load_lds16(BTl + boff[c] + k0, sBl + ldsoff[c]);
    }
    asm volatile("s_waitcnt vmcnt(0)" ::: "memory");
    __syncthreads();

#pragma unroll
    for (int kk = 0; kk < 2; kk++) {
      f16x8 a[4], as[4], bh[4], bl[4];
#pragma unroll
      for (int m = 0; m < 4; m++) {
        const int r = wr * 64 + m * 16 + fr;
        const int off = r * 64 + ((((kk << 2) | fkg) ^ (r & 7)) << 3);
        a[m] = *(const f16x8*)(sA + off);
        as[m] = a[m] * (_Float16)0.0009765625f;  // *2^-10, exact
      }
#pragma unroll
      for (int n = 0; n < 4; n++) {
        const int r = wc * 64 + n * 16 + fr;
        const int off = r * 64 + ((((kk << 2) | fkg) ^ (r & 7)) << 3);
        bh[n] = *(const f16x8*)(sBh + off);
        bl[n] = *(const f16x8*)(sBl + off);
      }
#pragma unroll
      for (int m = 0; m < 4; m++)
#pragma unroll
        for (int n = 0; n < 4; n++) {
          acc[m][n] = __builtin_amdgcn_mfma_f32_16x16x32_f16(a[m], bh[n], acc[m][n], 0, 0, 0);
          acc[m][n] = __builtin_amdgcn_mfma_f32_16x16x32_f16(as[m], bl[n], acc[m][n], 0, 0, 0);
        }
    }
    __syncthreads();
  }

  // epilogue: C/D layout col=lane&15, row=(lane>>4)*4+j (dtype-independent)
#pragma unroll
  for (int m = 0; m < 4; m++) {
    const int row = bm + wr * 64 + m * 16 + fkg * 4;
#pragma unroll
    for (int n = 0; n < 4; n++) {
      const int col = bn + wc * 64 + n * 16 + fr;
      const float bsv = bias[col];
#pragma unroll
      for (int j = 0; j < 4; j++)
        C[(size_t)(row + j) * Nn + col] = acc[m][n][j] + bsv;
    }
  }
}

// ---------------------------------------------------------------------------
// Vsum two-stage: part[b,chunk,d] = sum of 64 rows; then combine.
// ---------------------------------------------------------------------------
__global__ __launch_bounds__(256) void vsum_part(const float* __restrict__ v,
                                                 float* __restrict__ part) {
  const int b = blockIdx.x >> 4;
  const int chunk = blockIdx.x & 15;
  const int d4 = threadIdx.x * 4;
  const float* p = v + (size_t)b * N * LDQKV + (size_t)chunk * 64 * LDQKV + d4;
  float4 s = {0.f, 0.f, 0.f, 0.f};
#pragma unroll 8
  for (int n = 0; n < 64; n++) {
    float4 t = *(const float4*)(p + (size_t)n * LDQKV);
    s.x += t.x; s.y += t.y; s.z += t.z; s.w += t.w;
  }
  *(float4*)(part + (size_t)blockIdx.x * 1024 + d4) = s;
}

__global__ __launch_bounds__(256) void vsum_comb(const float* __restrict__ part,
                                                 float* __restrict__ vsum) {
  const int i = blockIdx.x * 256 + threadIdx.x;  // b*1024 + d
  const int b = i >> 10, d = i & 1023;
  float s = 0.f;
#pragma unroll
  for (int c = 0; c < 16; c++) s += part[(size_t)(b * 16 + c) * 1024 + d];
  vsum[i] = s;
}

// ---------------------------------------------------------------------------
// pass1: gather-dot over 32 keys, closed-form full-row softmax;
// writes p/base and the fp16 O-GEMM input plane directly.
// ---------------------------------------------------------------------------
__global__ __launch_bounds__(64) void attn_pass1(
    const float* __restrict__ qkv, const float* __restrict__ vsum,
    const int* __restrict__ graph, float* __restrict__ pbuf,
    float* __restrict__ basebuf, unsigned short* __restrict__ O16) {
  const int bid = blockIdx.x;  // (b*H + h)*N + n
  const int n = bid & (N - 1);
  const int h = (bid >> 10) & (H - 1);
  const int b = bid >> 14;
  const int lane = threadIdx.x;

  __shared__ float q_sh[DEPTH];
  __shared__ int g_sh[W];
  __shared__ float p_sh[W];

  const float* qrow = qkv + (size_t)(b * N + n) * LDQKV + h * DEPTH;
  q_sh[lane] = qrow[lane];
  if (lane < W) g_sh[lane] = graph[n * W + lane];
  __syncthreads();

  const int w = lane >> 1;
  const int half = lane & 1;
  const float* krow =
      qkv + 1024 + (size_t)(b * N + g_sh[w]) * LDQKV + h * DEPTH + half * 32;
  float acc = 0.f;
#pragma unroll
  for (int j4 = 0; j4 < 8; j4++) {
    float4 kv = *(const float4*)(krow + j4 * 4);
    const float* qh = &q_sh[half * 32 + j4 * 4];
    acc += kv.x * qh[0] + kv.y * qh[1] + kv.z * qh[2] + kv.w * qh[3];
  }
  acc += __shfl_xor(acc, 1);
  const float dot = acc * 0.125f;

  float m = dot;
#pragma unroll
  for (int off = 2; off < 64; off <<= 1) m = fmaxf(m, __shfl_xor(m, off));
  m = fmaxf(m, 0.f);

  const float e = expf(dot - m);
  float s = e;
#pragma unroll
  for (int off = 1; off < 64; off <<= 1) s += __shfl_xor(s, off);
  s *= 0.5f;

  const float em = expf(-m);
  const float Z = (float)(N - W) * em + s;
  const float inv = 1.f / Z;
  const float base = em * inv;
  const float pw = e * inv;

  if (half == 0) p_sh[w] = pw;
  __syncthreads();

  if (half == 0) pbuf[(size_t)bid * W + w] = pw;
  if (lane == 0) basebuf[bid] = base;

  const float* vbase = qkv + 2048;
  const int col = h * DEPTH + lane;
  float ov = base * vsum[b * D + col];
#pragma unroll 4
  for (int ww = 0; ww < W; ww++) {
    ov += (p_sh[ww] - base) *
          vbase[(size_t)(b * N + g_sh[ww]) * LDQKV + col];
  }
  _Float16 hh = (_Float16)ov;
  O16[(size_t)(b * N + n) * D + col] = __builtin_bit_cast(unsigned short, hh);
}

// ---------------------------------------------------------------------------
// attn row fill: base everywhere, p_w at graph positions. NT stores.
// ---------------------------------------------------------------------------
__global__ __launch_bounds__(256) void attn_fill(
    const float* __restrict__ pbuf, const float* __restrict__ basebuf,
    const int* __restrict__ graph, float* __restrict__ attn) {
  const int bid = blockIdx.x;
  const int n = bid & (N - 1);
  __shared__ float row[N];

  const float base = basebuf[bid];
  f32x4 b4 = {base, base, base, base};
  f32x4* row4 = (f32x4*)row;
  row4[threadIdx.x] = b4;
  __syncthreads();
  if (threadIdx.x < W) {
    const int g = graph[n * W + threadIdx.x];
    row[g] = pbuf[(size_t)bid * W + threadIdx.x];
  }
  __syncthreads();
  f32x4* dst = (f32x4*)(attn + (size_t)bid * N);
  __builtin_nontemporal_store(row4[threadIdx.x], dst + threadIdx.x);
}

// ---------------------------------------------------------------------------
extern "C" void kernel_launch(void* const* d_in, const int* in_sizes, int n_in,
                              void* d_out, int out_size, void* d_ws, size_t ws_size,
                              hipStream_t stream) {
  const float* hidden = (const float*)d_in[0];
  const float* wq = (const float*)d_in[1];
  const float* bq = (const float*)d_in[2];
  const float* wk = (const float*)d_in[3];
  const float* bk = (const float*)d_in[4];
  const float* wv = (const float*)d_in[5];
  const float* bv = (const float*)d_in[6];
  const float* wo = (const float*)d_in[7];
  const float* bo = (const float*)d_in[8];
  const int* graph = (const int*)d_in[9];

  float* out0 = (float*)d_out;                 // (B,N,D) final output
  float* attnp = out0 + (size_t)B * N * D;     // (B,H,N,N) — also scratch arena

  // scratch carved from attn region (64M floats; fully rewritten by attn_fill)
  const size_t M1 = (size_t)1024 * 1024;
  float* qkv = attnp;                                          // [4096][3072] f32
  unsigned short* A16 = (unsigned short*)(attnp + 12 * M1);    // [4096][1024] f16
  unsigned short* BTh = (unsigned short*)(attnp + 14 * M1);    // [3072][1024] f16
  unsigned short* BTl = (unsigned short*)(attnp + 15 * M1 + 512 * 1024);
  unsigned short* WoTh = (unsigned short*)(attnp + 17 * M1);   // [1024][1024] f16
  unsigned short* WoTl = (unsigned short*)(attnp + 17 * M1 + 512 * 1024);
  unsigned short* O16 = (unsigned short*)(attnp + 18 * M1);    // [4096][1024] f16
  float* biasq = attnp + 20 * M1;                              // 3072
  float* vpart = attnp + 20 * M1 + 8192;                       // [64][1024]

  // small workspace (proven size)
  float* pbuf = (float*)d_ws;                  // B*H*N*W
  float* basebuf = pbuf + (size_t)B * H * N * W;
  float* vsumb = basebuf + (size_t)B * H * N;

  // converts
  cvt_half<<<2048, 256, 0, stream>>>(hidden, A16);
  txp_cvt_h<<<256, 256, 0, stream>>>(wq, BTh, BTl, 0);
  txp_cvt_h<<<256, 256, 0, stream>>>(wk, BTh, BTl, 1024);
  txp_cvt_h<<<256, 256, 0, stream>>>(wv, BTh, BTl, 2048);
  txp_cvt_h<<<256, 256, 0, stream>>>(wo, WoTh, WoTl, 0);
  bias_concat<<<12, 256, 0, stream>>>(bq, bk, bv, biasq);

  // fused projection: qkv = hidden @ [Wq | Wk | Wv] + [bq | bk | bv]
  gemm_f16<<<dim3(24, 32), 256, 0, stream>>>(A16, BTh, BTl, biasq,
                                             qkv, 1024, 3072);

  vsum_part<<<64, 256, 0, stream>>>(qkv + 2048, vpart);
  vsum_comb<<<16, 256, 0, stream>>>(vpart, vsumb);

  attn_pass1<<<B * H * N, 64, 0, stream>>>(qkv, vsumb, graph, pbuf, basebuf,
                                           O16);

  // O-projection
  gemm_f16<<<dim3(8, 32), 256, 0, stream>>>(O16, WoTh, WoTl, bo,
                                            out0, 1024, 1024);

  attn_fill<<<B * H * N, 256, 0, stream>>>(pbuf, basebuf, graph, attnp);
}

// Round 8
// 209.124 us; speedup vs baseline: 1.8516x; 1.2455x over previous
//
#include <hip/hip_runtime.h>
#include <hip/hip_bf16.h>

constexpr int B = 4;
constexpr int N = 1024;
constexpr int D = 1024;
constexpr int H = 16;
constexpr int DEPTH = 64;
constexpr int W = 32;
constexpr int LDQKV = 3072;   // fused q|k|v row stride (f16 elements)

typedef _Float16 f16x8 __attribute__((ext_vector_type(8)));
typedef float f32x4 __attribute__((ext_vector_type(4)));
typedef unsigned short us8 __attribute__((ext_vector_type(8)));
typedef unsigned short us4 __attribute__((ext_vector_type(4)));

__device__ __forceinline__ float h2f(unsigned short u) {
  return (float)__builtin_bit_cast(_Float16, u);
}

// ---------------------------------------------------------------------------
// async global->LDS, 16B per lane (wave-uniform LDS base, HW adds lane*16)
// ---------------------------------------------------------------------------
__device__ __forceinline__ void load_lds16(const void* g, void* l) {
  unsigned int lo = (unsigned int)(unsigned long long)l;
  __builtin_amdgcn_global_load_lds(
      (const __attribute__((address_space(1))) unsigned int*)g,
      (__attribute__((address_space(3))) unsigned int*)lo, 16, 0, 0);
}

// ---------------------------------------------------------------------------
// fp32 -> fp16 (single hi plane), 8 elems/thread
// ---------------------------------------------------------------------------
__global__ __launch_bounds__(256) void cvt_half(const float* __restrict__ x,
                                                unsigned short* __restrict__ o) {
  const size_t i = ((size_t)blockIdx.x * 256 + threadIdx.x) * 8;
  float4 a = *(const float4*)(x + i);
  float4 b = *(const float4*)(x + i + 4);
  float xs[8] = {a.x, a.y, a.z, a.w, b.x, b.y, b.z, b.w};
  us8 hv;
#pragma unroll
  for (int j = 0; j < 8; j++) {
    _Float16 h = (_Float16)xs[j];
    hv[j] = __builtin_bit_cast(unsigned short, h);
  }
  *(us8*)(o + i) = hv;
}

// ---------------------------------------------------------------------------
// weight [K=1024][N=1024] -> transposed fp16 split BT[rowOff+n][k]:
// hi = (f16)w ; lo = (f16)((w - hi) * 1024)   (scaled to stay fp16-normal)
// ---------------------------------------------------------------------------
__global__ __launch_bounds__(256) void txp_cvt_h(const float* __restrict__ w,
                                                 unsigned short* __restrict__ bth,
                                                 unsigned short* __restrict__ btl,
                                                 int rowOff) {
  __shared__ float sf[64][65];
  const int t = threadIdx.x;
  const int tn = (blockIdx.x & 15) * 64;  // src col block
  const int tk = (blockIdx.x >> 4) * 64;  // src row block
#pragma unroll
  for (int i = 0; i < 4; i++) {
    int f = i * 256 + t;
    int r = f >> 4, c4 = (f & 15) * 4;
    float4 v = *(const float4*)(w + (size_t)(tk + r) * 1024 + tn + c4);
    sf[r][c4 + 0] = v.x; sf[r][c4 + 1] = v.y;
    sf[r][c4 + 2] = v.z; sf[r][c4 + 3] = v.w;
  }
  __syncthreads();
  const int n = t >> 2;            // out row (src col)
  const int kc = (t & 3) * 16;     // k chunk
  us8 hv[2], lv[2];
#pragma unroll
  for (int half = 0; half < 2; half++) {
#pragma unroll
    for (int j = 0; j < 8; j++) {
      float x = sf[kc + half * 8 + j][n];
      _Float16 h = (_Float16)x;
      _Float16 l = (_Float16)((x - (float)h) * 1024.0f);
      hv[half][j] = __builtin_bit_cast(unsigned short, h);
      lv[half][j] = __builtin_bit_cast(unsigned short, l);
    }
  }
  size_t dst = (size_t)(rowOff + tn + n) * 1024 + tk + kc;
  *(us8*)(bth + dst) = hv[0];
  *(us8*)(bth + dst + 8) = hv[1];
  *(us8*)(btl + dst) = lv[0];
  *(us8*)(btl + dst + 8) = lv[1];
}

__global__ void bias_concat(const float* __restrict__ bq, const float* __restrict__ bk,
                            const float* __restrict__ bv, float* __restrict__ dst) {
  int i = blockIdx.x * 256 + threadIdx.x;
  dst[i] = i < 1024 ? bq[i] : (i < 2048 ? bk[i - 1024] : bv[i - 2048]);
}

// ---------------------------------------------------------------------------
// fp16 2-term split MFMA GEMM, 2-PHASE double-buffered (T3 minimum recipe):
//   C = Ah@Bh + (Ah*2^-10)@(Bl*2^10) + bias
// 128x128 tile, BK=32, 4 waves, 16x16x32 f16 MFMA, 4x4 frags/wave.
// 2x3 LDS planes [128][32] (48 KB total -> 3 blocks/CU). STAGE(t+1) issued
// BEFORE compute(t); the compiler's pre-barrier vmcnt drain then hides load
// latency under the 32-MFMA compute phase. Granule swizzle k'=k^((r>>1)&3)
// on global source + ds_read (round-2 verified). T1 XCD swizzle; T5 setprio.
// ---------------------------------------------------------------------------
template <bool F16OUT>
__global__ __launch_bounds__(256) void gemm_f16(
    const unsigned short* __restrict__ A16, const unsigned short* __restrict__ BTh,
    const unsigned short* __restrict__ BTl, const float* __restrict__ bias,
    void* __restrict__ Cout, int K, int Nn) {
  __shared__ __align__(16) unsigned short sA[2 * 128 * 32];
  __shared__ __align__(16) unsigned short sBh[2 * 128 * 32];
  __shared__ __align__(16) unsigned short sBl[2 * 128 * 32];

  const int tid = threadIdx.x;
  const int lane = tid & 63;
  const int wave = tid >> 6;
  const int wr = wave >> 1, wc = wave & 1;

  // T1 XCD-aware swizzle (nwg % 8 == 0 for both launches)
  const int gx = gridDim.x;
  const int nwg = gx * gridDim.y;
  int bid = blockIdx.y * gx + blockIdx.x;
  bid = (bid & 7) * (nwg >> 3) + (bid >> 3);
  const int bm = (bid / gx) * 128;
  const int bn = (bid % gx) * 128;

  // staging: plane = 8KB = 8 chunks of (64 lanes x 16B); wave stages chunks
  // {wave, wave+4}. Pre-swizzled global source (rule #21), linear LDS dest.
  size_t aoff[2], boff[2];
  int ldsoff[2];
#pragma unroll
  for (int c = 0; c < 2; c++) {
    const int chunk = wave + 4 * c;
    const int e = chunk * 512 + lane * 8;   // linear LDS element
    const int r = e >> 5;                   // tile row
    const int kpos = (e >> 3) & 3;          // granule position in row
    const int ksrc = kpos ^ ((r >> 1) & 3); // swizzle: source granule
    aoff[c] = (size_t)(bm + r) * K + ksrc * 8;
    boff[c] = (size_t)(bn + r) * K + ksrc * 8;
    ldsoff[c] = chunk * 512;
  }

  const int fr = lane & 15;
  const int fkg = lane >> 4;

  // precompute ds_read offsets (within one buffer)
  int aroff[4], broff[4];
#pragma unroll
  for (int m = 0; m < 4; m++) {
    const int ra = wr * 64 + m * 16 + fr;
    aroff[m] = ra * 32 + ((fkg ^ ((ra >> 1) & 3)) << 3);
    const int rb = wc * 64 + m * 16 + fr;
    broff[m] = rb * 32 + ((fkg ^ ((rb >> 1) & 3)) << 3);
  }

  f32x4 acc[4][4] = {};

  const int NT = K >> 5;
  // prologue: stage tile 0 into buffer 0
#pragma unroll
  for (int c = 0; c < 2; c++) {
    load_lds16(A16 + aoff[c], sA + ldsoff[c]);
    load_lds16(BTh + boff[c], sBh + ldsoff[c]);
    load_lds16(BTl + boff[c], sBl + ldsoff[c]);
  }
  __syncthreads();  // compiler drains vmcnt(0) before barrier

  int cur = 0;
  for (int t = 0; t < NT; t++) {
    const int bo_ = cur * (128 * 32);
    const int nx_ = (cur ^ 1) * (128 * 32);
    if (t + 1 < NT) {  // issue next-tile stage BEFORE compute (overlap)
      const int k0 = (t + 1) << 5;
#pragma unroll
      for (int c = 0; c < 2; c++) {
        load_lds16(A16 + aoff[c] + k0, sA + nx_ + ldsoff[c]);
        load_lds16(BTh + boff[c] + k0, sBh + nx_ + ldsoff[c]);
        load_lds16(BTl + boff[c] + k0, sBl + nx_ + ldsoff[c]);
      }
    }
    f16x8 a[4], as_[4], bh[4], bl[4];
#pragma unroll
    for (int m = 0; m < 4; m++) {
      a[m] = *(const f16x8*)(sA + bo_ + aroff[m]);
      as_[m] = a[m] * (_Float16)0.0009765625f;  // *2^-10, exact
    }
#pragma unroll
    for (int n = 0; n < 4; n++) {
      bh[n] = *(const f16x8*)(sBh + bo_ + broff[n]);
      bl[n] = *(const f16x8*)(sBl + bo_ + broff[n]);
    }
    __builtin_amdgcn_s_setprio(1);
#pragma unroll
    for (int m = 0; m < 4; m++)
#pragma unroll
      for (int n = 0; n < 4; n++) {
        acc[m][n] = __builtin_amdgcn_mfma_f32_16x16x32_f16(a[m], bh[n], acc[m][n], 0, 0, 0);
        acc[m][n] = __builtin_amdgcn_mfma_f32_16x16x32_f16(as_[m], bl[n], acc[m][n], 0, 0, 0);
      }
    __builtin_amdgcn_s_setprio(0);
    __syncthreads();  // drains staging vmcnt + all waves' ds_reads
    cur ^= 1;
  }

  // epilogue: C/D layout col=lane&15, row=(lane>>4)*4+j
#pragma unroll
  for (int m = 0; m < 4; m++) {
    const int row = bm + wr * 64 + m * 16 + fkg * 4;
#pragma unroll
    for (int n = 0; n < 4; n++) {
      const int col = bn + wc * 64 + n * 16 + fr;
      const float bsv = bias[col];
#pragma unroll
      for (int j = 0; j < 4; j++) {
        const float v = acc[m][n][j] + bsv;
        if constexpr (F16OUT) {
          ((unsigned short*)Cout)[(size_t)(row + j) * Nn + col] =
              __builtin_bit_cast(unsigned short, (_Float16)v);
        } else {
          ((float*)Cout)[(size_t)(row + j) * Nn + col] = v;
        }
      }
    }
  }
}

// ---------------------------------------------------------------------------
// Vsum two-stage over fp16 v: part[b,chunk,d] = sum of 64 rows; then combine.
// ---------------------------------------------------------------------------
__global__ __launch_bounds__(256) void vsum_part(const unsigned short* __restrict__ v,
                                                 float* __restrict__ part) {
  const int b = blockIdx.x >> 4;
  const int chunk = blockIdx.x & 15;
  const int d4 = threadIdx.x * 4;
  const unsigned short* p =
      v + (size_t)b * N * LDQKV + (size_t)chunk * 64 * LDQKV + d4;
  float4 s = {0.f, 0.f, 0.f, 0.f};
#pragma unroll 8
  for (int n = 0; n < 64; n++) {
    us4 t = *(const us4*)(p + (size_t)n * LDQKV);
    s.x += h2f(t[0]); s.y += h2f(t[1]); s.z += h2f(t[2]); s.w += h2f(t[3]);
  }
  *(float4*)(part + (size_t)blockIdx.x * 1024 + d4) = s;
}

__global__ __launch_bounds__(256) void vsum_comb(const float* __restrict__ part,
                                                 float* __restrict__ vsum) {
  const int i = blockIdx.x * 256 + threadIdx.x;  // b*1024 + d
  const int b = i >> 10, d = i & 1023;
  float s = 0.f;
#pragma unroll
  for (int c = 0; c < 16; c++) s += part[(size_t)(b * 16 + c) * 1024 + d];
  vsum[i] = s;
}

// ---------------------------------------------------------------------------
// pass1: gather-dot over 32 keys (fp16 qkv), closed-form full-row softmax;
// writes p/base and the fp16 O-GEMM input plane directly.
// ---------------------------------------------------------------------------
__global__ __launch_bounds__(64) void attn_pass1(
    const unsigned short* __restrict__ qkv16, const float* __restrict__ vsum,
    const int* __restrict__ graph, float* __restrict__ pbuf,
    float* __restrict__ basebuf, unsigned short* __restrict__ O16) {
  const int bid = blockIdx.x;  // (b*H + h)*N + n
  const int n = bid & (N - 1);
  const int h = (bid >> 10) & (H - 1);
  const int b = bid >> 14;
  const int lane = threadIdx.x;

  __shared__ float q_sh[DEPTH];
  __shared__ int g_sh[W];
  __shared__ float p_sh[W];

  const unsigned short* qrow = qkv16 + (size_t)(b * N + n) * LDQKV + h * DEPTH;
  q_sh[lane] = h2f(qrow[lane]);
  if (lane < W) g_sh[lane] = graph[n * W + lane];
  __syncthreads();

  const int w = lane >> 1;
  const int half = lane & 1;
  const unsigned short* krow =
      qkv16 + 1024 + (size_t)(b * N + g_sh[w]) * LDQKV + h * DEPTH + half * 32;
  float acc = 0.f;
#pragma unroll
  for (int j8 = 0; j8 < 4; j8++) {
    us8 kv = *(const us8*)(krow + j8 * 8);
    const float* qh = &q_sh[half * 32 + j8 * 8];
#pragma unroll
    for (int e = 0; e < 8; e++) acc += h2f(kv[e]) * qh[e];
  }
  acc += __shfl_xor(acc, 1);
  const float dot = acc * 0.125f;

  float m = dot;
#pragma unroll
  for (int off = 2; off < 64; off <<= 1) m = fmaxf(m, __shfl_xor(m, off));
  m = fmaxf(m, 0.f);

  const float e = expf(dot - m);
  float s = e;
#pragma unroll
  for (int off = 1; off < 64; off <<= 1) s += __shfl_xor(s, off);
  s *= 0.5f;

  const float em = expf(-m);
  const float Z = (float)(N - W) * em + s;
  const float inv = 1.f / Z;
  const float base = em * inv;
  const float pw = e * inv;

  if (half == 0) p_sh[w] = pw;
  __syncthreads();

  if (half == 0) pbuf[(size_t)bid * W + w] = pw;
  if (lane == 0) basebuf[bid] = base;

  const unsigned short* vbase = qkv16 + 2048;
  const int col = h * DEPTH + lane;
  float ov = base * vsum[b * D + col];
#pragma unroll 4
  for (int ww = 0; ww < W; ww++) {
    ov += (p_sh[ww] - base) *
          h2f(vbase[(size_t)(b * N + g_sh[ww]) * LDQKV + col]);
  }
  _Float16 hh = (_Float16)ov;
  O16[(size_t)(b * N + n) * D + col] = __builtin_bit_cast(unsigned short, hh);
}

// ---------------------------------------------------------------------------
// attn row fill: base everywhere, p_w at graph positions. NT stores.
// ---------------------------------------------------------------------------
__global__ __launch_bounds__(256) void attn_fill(
    const float* __restrict__ pbuf, const float* __restrict__ basebuf,
    const int* __restrict__ graph, float* __restrict__ attn) {
  const int bid = blockIdx.x;
  const int n = bid & (N - 1);
  __shared__ float row[N];

  const float base = basebuf[bid];
  f32x4 b4 = {base, base, base, base};
  f32x4* row4 = (f32x4*)row;
  row4[threadIdx.x] = b4;
  __syncthreads();
  if (threadIdx.x < W) {
    const int g = graph[n * W + threadIdx.x];
    row[g] = pbuf[(size_t)bid * W + threadIdx.x];
  }
  __syncthreads();
  f32x4* dst = (f32x4*)(attn + (size_t)bid * N);
  __builtin_nontemporal_store(row4[threadIdx.x], dst + threadIdx.x);
}

// ---------------------------------------------------------------------------
extern "C" void kernel_launch(void* const* d_in, const int* in_sizes, int n_in,
                              void* d_out, int out_size, void* d_ws, size_t ws_size,
                              hipStream_t stream) {
  const float* hidden = (const float*)d_in[0];
  const float* wq = (const float*)d_in[1];
  const float* bq = (const float*)d_in[2];
  const float* wk = (const float*)d_in[3];
  const float* bk = (const float*)d_in[4];
  const float* wv = (const float*)d_in[5];
  const float* bv = (const float*)d_in[6];
  const float* wo = (const float*)d_in[7];
  const float* bo = (const float*)d_in[8];
  const int* graph = (const int*)d_in[9];

  float* out0 = (float*)d_out;                 // (B,N,D) final output
  float* attnp = out0 + (size_t)B * N * D;     // (B,H,N,N) — also scratch arena

  // scratch carved from attn region (64M floats; fully rewritten by attn_fill)
  const size_t M1 = (size_t)1024 * 1024;
  unsigned short* qkv16 = (unsigned short*)attnp;              // [4096][3072] f16 (6M f)
  unsigned short* A16 = (unsigned short*)(attnp + 6 * M1);     // [4096][1024] f16 (2M f)
  unsigned short* BTh = (unsigned short*)(attnp + 8 * M1);     // [3072][1024] f16 (1.5M f)
  unsigned short* BTl = (unsigned short*)(attnp + 10 * M1);    // 1.5M f
  unsigned short* WoTh = (unsigned short*)(attnp + 12 * M1);   // [1024][1024] f16
  unsigned short* WoTl = (unsigned short*)(attnp + 13 * M1);
  unsigned short* O16 = (unsigned short*)(attnp + 14 * M1);    // [4096][1024] f16 (2M f)
  float* biasq = attnp + 16 * M1;                              // 3072
  float* vpart = attnp + 16 * M1 + 8192;                       // [64][1024]

  // small workspace (proven size)
  float* pbuf = (float*)d_ws;                  // B*H*N*W
  float* basebuf = pbuf + (size_t)B * H * N * W;
  float* vsumb = basebuf + (size_t)B * H * N;

  // converts
  cvt_half<<<2048, 256, 0, stream>>>(hidden, A16);
  txp_cvt_h<<<256, 256, 0, stream>>>(wq, BTh, BTl, 0);
  txp_cvt_h<<<256, 256, 0, stream>>>(wk, BTh, BTl, 1024);
  txp_cvt_h<<<256, 256, 0, stream>>>(wv, BTh, BTl, 2048);
  txp_cvt_h<<<256, 256, 0, stream>>>(wo, WoTh, WoTl, 0);
  bias_concat<<<12, 256, 0, stream>>>(bq, bk, bv, biasq);

  // fused projection: qkv16 = f16(hidden @ [Wq | Wk | Wv] + [bq | bk | bv])
  gemm_f16<true><<<dim3(24, 32), 256, 0, stream>>>(A16, BTh, BTl, biasq,
                                                   qkv16, 1024, 3072);

  vsum_part<<<64, 256, 0, stream>>>(qkv16 + 2048, vpart);
  vsum_comb<<<16, 256, 0, stream>>>(vpart, vsumb);

  attn_pass1<<<B * H * N, 64, 0, stream>>>(qkv16, vsumb, graph, pbuf, basebuf,
                                           O16);

  // O-projection (fp32 out)
  gemm_f16<false><<<dim3(8, 32), 256, 0, stream>>>(O16, WoTh, WoTl, bo,
                                                   out0, 1024, 1024);

  attn_fill<<<B * H * N, 256, 0, stream>>>(pbuf, basebuf, graph, attnp);
}